// Round 1
// baseline (86.095 us; speedup 1.0000x reference)
//
#include <hip/hip_runtime.h>

// Problem: out[b][j] = sum_i spikes[b][i] * W[i][j]
//   spikes: [8, 8192] fp32, W: [8192, 8192] fp32 row-major, out: [8, 8192] fp32
// Memory-bound: 256 MiB of W streamed once, 4 FLOP/byte.
// Strategy: split-K across blocks + atomicAdd into zeroed d_out.
//   - 256 thr/block, 2 cols/thread (float2 loads, coalesced 8B/lane)
//   - KCHUNK=128 -> grid (16 col-blocks, 64 k-chunks) = 1024 blocks (16 waves/CU)
//   - spikes chunk staged in LDS, broadcast reads (conflict-free)

constexpr int N_PREV = 8192;
constexpr int N_HID  = 8192;
constexpr int BATCH  = 8;
constexpr int KCHUNK = 128;
constexpr int TPB    = 256;
constexpr int COLS_PER_BLOCK = TPB * 2;  // 512

__global__ __launch_bounds__(TPB) void snn_gemm_splitk(
    const float* __restrict__ spikes,
    const float* __restrict__ W,
    float* __restrict__ out) {
  __shared__ float s_sp[BATCH][KCHUNK];

  const int cb = blockIdx.x;           // column-block index
  const int kc = blockIdx.y;           // k-chunk index
  const int k0 = kc * KCHUNK;
  const int col = cb * COLS_PER_BLOCK + threadIdx.x * 2;

  // Stage this k-chunk of spikes: 8 x 128 floats = 1024 elems, 4 per thread.
  for (int t = threadIdx.x; t < BATCH * KCHUNK; t += TPB) {
    const int b = t >> 7;          // t / KCHUNK
    const int k = t & (KCHUNK - 1);
    s_sp[b][k] = spikes[b * N_PREV + k0 + k];
  }
  __syncthreads();

  float acc[BATCH][2];
  #pragma unroll
  for (int b = 0; b < BATCH; ++b) { acc[b][0] = 0.f; acc[b][1] = 0.f; }

  const float* wp = W + (size_t)k0 * N_HID + col;
  #pragma unroll 4
  for (int k = 0; k < KCHUNK; ++k) {
    const float2 w = *reinterpret_cast<const float2*>(wp);
    wp += N_HID;
    #pragma unroll
    for (int b = 0; b < BATCH; ++b) {
      const float s = s_sp[b][k];
      acc[b][0] += s * w.x;
      acc[b][1] += s * w.y;
    }
  }

  #pragma unroll
  for (int b = 0; b < BATCH; ++b) {
    atomicAdd(&out[b * N_HID + col + 0], acc[b][0]);
    atomicAdd(&out[b * N_HID + col + 1], acc[b][1]);
  }
}

extern "C" void kernel_launch(void* const* d_in, const int* in_sizes, int n_in,
                              void* d_out, int out_size, void* d_ws, size_t ws_size,
                              hipStream_t stream) {
  const float* spikes = (const float*)d_in[0];   // [8, 8192]
  const float* W      = (const float*)d_in[1];   // [8192, 8192]
  float* out          = (float*)d_out;           // [8, 8192]

  // Harness poisons d_out once and never re-poisons between replays; we
  // accumulate with atomics, so zero it each call (async, graph-capturable).
  hipMemsetAsync(out, 0, (size_t)out_size * sizeof(float), stream);

  dim3 grid(N_HID / COLS_PER_BLOCK, N_PREV / KCHUNK);  // (16, 64)
  dim3 block(TPB);
  snn_gemm_splitk<<<grid, block, 0, stream>>>(spikes, W, out);
}